// Round 5
// baseline (107.879 us; speedup 1.0000x reference)
//
#include <hip/hip_runtime.h>
#include <hip/hip_bf16.h>

typedef __attribute__((ext_vector_type(8))) short bf16x8;   // 8 bf16 (MFMA A/B frag)
typedef __attribute__((ext_vector_type(4))) float f32x4;    // MFMA C/D frag

static __device__ __forceinline__ unsigned short f2b(float f) {
  union { __hip_bfloat16 h; unsigned short u; } cv;
  cv.h = __float2bfloat16(f);
  return cv.u;
}

static __device__ __forceinline__ bf16x8 pack8(float4 a, float4 b) {
  bf16x8 r;
  r[0] = (short)f2b(a.x); r[1] = (short)f2b(a.y); r[2] = (short)f2b(a.z); r[3] = (short)f2b(a.w);
  r[4] = (short)f2b(b.x); r[5] = (short)f2b(b.y); r[6] = (short)f2b(b.z); r[7] = (short)f2b(b.w);
  return r;
}

// ---- prep: weights -> bf16 W^T in ws ----
// wt layout (bf16 elems): WT1 @0 (256x128), WT2 @32768 (256x256), WT3 @98304 (256x256)
__global__ void __launch_bounds__(256) gnn_prep(const float* __restrict__ W1,
                                                const float* __restrict__ W2,
                                                const float* __restrict__ W3,
                                                unsigned short* __restrict__ wt) {
  int idx = blockIdx.x * 256 + threadIdx.x;   // 0..65535
  unsigned short* wt1 = wt;
  unsigned short* wt2 = wt + 32768;
  unsigned short* wt3 = wt + 98304;
  if (idx < 32768) { int d = idx >> 8, h = idx & 255; wt1[h * 128 + d] = f2b(W1[idx]); }
  { int d = idx >> 8, h = idx & 255; wt2[h * 256 + d] = f2b(W2[idx]); wt3[h * 256 + d] = f2b(W3[idx]); }
}

// ---- main: one block per graph, 1024 thr (16 waves), 80 KB LDS, 1 block/CU ----
// sXT byte-swizzle: 16B granule ^= (d&15); sAggC: granule ^= (i&7). Same XOR write+read.
#define XS(d, colb) ((d) * 128 + ((((colb)) ^ (((d) & 15) << 4)) >> 1))
#define AGS(i, colb) ((i) * 64 + ((((colb)) ^ (((i) & 7) << 4)) >> 1))

__global__ void __launch_bounds__(1024, 4) gnn_main(
    const float* __restrict__ xin, const float* __restrict__ adjg,
    const float* __restrict__ b1, const float* __restrict__ b2,
    const float* __restrict__ b3, const float* __restrict__ Wh,
    const float* __restrict__ bh, const unsigned short* __restrict__ wt,
    float* __restrict__ out) {
  __shared__ unsigned short sXT[256 * 128];    // X^T [d][j], swizzled; 64 KB
  __shared__ unsigned short sAggC[128 * 64];   // AGG chunk [i][dloc], swizzled; 16 KB

  const int g = blockIdx.x, tid = threadIdx.x;
  const int lane = tid & 63, w = tid >> 6;     // 16 waves
  const int l15 = lane & 15, l4 = lane >> 4;
  const int wm = w & 1;    // A-phase: d-half (0..1)
  const int wi = w >> 1;   // A-phase: i-group (0..7)
  const int wr = w & 3;    // B-phase: i-group (0..3)
  const int wc = w >> 2;   // B-phase: h-group (0..3)

  const float* xg = xin + (size_t)g * 16384;
  const float* ag = adjg + (size_t)g * 16384;

  // ---- adj B-fragments: wave handles i in [wi*16, wi*16+16); loaded once, 16 regs ----
  bf16x8 adjF[4];
  {
    int ir = wi * 16 + l15;
#pragma unroll
    for (int ks = 0; ks < 4; ++ks) {
      float4 a0 = *(const float4*)(ag + ir * 128 + ks * 32 + l4 * 8);
      float4 a1 = *(const float4*)(ag + ir * 128 + ks * 32 + l4 * 8 + 4);
      adjF[ks] = pack8(a0, a1);
    }
  }
  // ---- in-kernel X transpose: X[j][d] fp32 -> sXT[d][j] bf16 (4x4 register-blocked) ----
  {
    int db = tid & 31, jb = tid >> 5;          // 32 d-blocks x 32 j-blocks
    int d0 = db * 4, j0 = jb * 4;
    float4 r0 = *(const float4*)(xg + (j0 + 0) * 128 + d0);
    float4 r1 = *(const float4*)(xg + (j0 + 1) * 128 + d0);
    float4 r2 = *(const float4*)(xg + (j0 + 2) * 128 + d0);
    float4 r3 = *(const float4*)(xg + (j0 + 3) * 128 + d0);
    *(ushort4*)&sXT[XS(d0 + 0, j0 * 2)] = make_ushort4(f2b(r0.x), f2b(r1.x), f2b(r2.x), f2b(r3.x));
    *(ushort4*)&sXT[XS(d0 + 1, j0 * 2)] = make_ushort4(f2b(r0.y), f2b(r1.y), f2b(r2.y), f2b(r3.y));
    *(ushort4*)&sXT[XS(d0 + 2, j0 * 2)] = make_ushort4(f2b(r0.z), f2b(r1.z), f2b(r2.z), f2b(r3.z));
    *(ushort4*)&sXT[XS(d0 + 3, j0 * 2)] = make_ushort4(f2b(r0.w), f2b(r1.w), f2b(r2.w), f2b(r3.w));
  }
  __syncthreads();

  f32x4 accB[2][4];

  for (int l = 0; l < 3; ++l) {
    const int Din = (l == 0) ? 128 : 256;
    const int nck = Din >> 6;
    const unsigned short* wtl = (l == 0) ? wt : (l == 1) ? wt + 32768 : wt + 98304;

#pragma unroll
    for (int mi = 0; mi < 2; ++mi)
#pragma unroll
      for (int ni = 0; ni < 4; ++ni) accB[mi][ni] = (f32x4){0.f, 0.f, 0.f, 0.f};

    for (int c = 0; c < nck; ++c) {
      // ---- phase A': AGGT[dloc][i] = sum_j XT[c*64+dloc][j] * adj[j][i] (adj symmetric) ----
      f32x4 accA[2];
      accA[0] = (f32x4){0.f, 0.f, 0.f, 0.f};
      accA[1] = (f32x4){0.f, 0.f, 0.f, 0.f};
#pragma unroll
      for (int ks = 0; ks < 4; ++ks) {
        bf16x8 a[2];
#pragma unroll
        for (int mi = 0; mi < 2; ++mi) {
          int dr = c * 64 + wm * 32 + mi * 16 + l15;
          a[mi] = *(const bf16x8*)&sXT[XS(dr, ks * 64 + l4 * 16)];
        }
#pragma unroll
        for (int mi = 0; mi < 2; ++mi)
          accA[mi] = __builtin_amdgcn_mfma_f32_16x16x32_bf16(a[mi], adjF[ks], accA[mi], 0, 0, 0);
      }
#pragma unroll
      for (int mi = 0; mi < 2; ++mi) {
        int dloc = wm * 32 + mi * 16 + l4 * 4;
        int i = wi * 16 + l15;
        f32x4 v = accA[mi];
        *(ushort4*)&sAggC[AGS(i, 2 * dloc)] =
            make_ushort4(f2b(v[0]), f2b(v[1]), f2b(v[2]), f2b(v[3]));
      }
      __syncthreads();
      // ---- phase B: accB += AGG_chunk @ W_chunk (wf per-ni from L2-hot ws) ----
#pragma unroll
      for (int ks = 0; ks < 2; ++ks) {
        bf16x8 aB[2];
#pragma unroll
        for (int mi = 0; mi < 2; ++mi) {
          int ir = wr * 32 + mi * 16 + l15;
          aB[mi] = *(const bf16x8*)&sAggC[AGS(ir, ks * 64 + l4 * 16)];
        }
#pragma unroll
        for (int ni = 0; ni < 4; ++ni) {
          int hr = wc * 64 + ni * 16 + l15;
          bf16x8 wf = *(const bf16x8*)(wtl + hr * Din + c * 64 + ks * 32 + l4 * 8);
#pragma unroll
          for (int mi = 0; mi < 2; ++mi)
            accB[mi][ni] = __builtin_amdgcn_mfma_f32_16x16x32_bf16(aB[mi], wf, accB[mi][ni], 0, 0, 0);
        }
      }
      __syncthreads();
    } // chunks

    if (l < 2) {
      const float* bl = (l == 0) ? b1 : b2;
      // H[i][h] -> sXT[h][i] (next layer's X^T), 8B swizzled writes
#pragma unroll
      for (int ni = 0; ni < 4; ++ni) {
        int h = wc * 64 + ni * 16 + l15;
        float bias = bl[h];
#pragma unroll
        for (int mi = 0; mi < 2; ++mi) {
          int i0 = wr * 32 + mi * 16 + l4 * 4;
          f32x4 v = accB[mi][ni];
          *(ushort4*)&sXT[XS(h, 2 * i0)] = make_ushort4(
              f2b(fmaxf(v[0] + bias, 0.f)), f2b(fmaxf(v[1] + bias, 0.f)),
              f2b(fmaxf(v[2] + bias, 0.f)), f2b(fmaxf(v[3] + bias, 0.f)));
        }
      }
      __syncthreads();
    } else {
      // ---- mean pool + linear head (fp32) ----
      float* sPool = (float*)sAggC;   // [4 wr][256 h]
      float ps[4];
#pragma unroll
      for (int ni = 0; ni < 4; ++ni) {
        float bias = b3[wc * 64 + ni * 16 + l15];
        float s = 0.f;
#pragma unroll
        for (int mi = 0; mi < 2; ++mi)
#pragma unroll
          for (int r = 0; r < 4; ++r) s += fmaxf(accB[mi][ni][r] + bias, 0.f);
        s += __shfl_xor(s, 16);   // sum over l4 bit 0
        s += __shfl_xor(s, 32);   // sum over l4 bit 1
        ps[ni] = s;
      }
      if (l4 == 0) {
#pragma unroll
        for (int ni = 0; ni < 4; ++ni)
          sPool[wr * 256 + wc * 64 + ni * 16 + l15] = ps[ni];
      }
      __syncthreads();
      if (w == 0) {
        float acc = 0.f;
#pragma unroll
        for (int q = 0; q < 4; ++q) {
          int h = lane + q * 64;
          float p = sPool[h] + sPool[256 + h] + sPool[512 + h] + sPool[768 + h];
          acc += p * Wh[h];
        }
#pragma unroll
        for (int off = 32; off > 0; off >>= 1) acc += __shfl_xor(acc, off);
        if (lane == 0) out[g] = acc * (1.0f / 128.0f) + bh[0];
      }
    }
  }
}

extern "C" void kernel_launch(void* const* d_in, const int* in_sizes, int n_in,
                              void* d_out, int out_size, void* d_ws, size_t ws_size,
                              hipStream_t stream) {
  const float* xin = (const float*)d_in[0];   // node_features [512,128,128]
  const float* adj = (const float*)d_in[1];   // adj [512,128,128]
  const float* W1  = (const float*)d_in[2];
  const float* b1  = (const float*)d_in[3];
  const float* W2  = (const float*)d_in[4];
  const float* b2  = (const float*)d_in[5];
  const float* W3  = (const float*)d_in[6];
  const float* b3  = (const float*)d_in[7];
  const float* Wh  = (const float*)d_in[8];
  const float* bh  = (const float*)d_in[9];

  unsigned short* wt = (unsigned short*)d_ws;   // 327,680 B of bf16 W^T

  gnn_prep<<<256, 256, 0, stream>>>(W1, W2, W3, wt);
  gnn_main<<<512, 1024, 0, stream>>>(xin, adj, b1, b2, b3, Wh, bh, wt, (float*)d_out);
}